// Round 17
// baseline (717.723 us; speedup 1.0000x reference)
//
#include <hip/hip_runtime.h>

#define DEVFN __device__ __forceinline__

constexpr int GN = 100000, GE = 3200000;
constexpr int GE1 = GE + GN;          // 3,300,000
constexpr int GE2 = GE1 + GN;         // 3,400,000
constexpr int GEMB = 128, GHID = 16, GOUT = 32;
constexpr float GNEG = 0.2f;
constexpr float GEA2 = 100000.f / 3300000.f;   // mean(alpha1) = N/E1 exactly

constexpr long long G0 = (long long)GN * GOUT;   //  3,200,000  (out end)
constexpr long long G1 = G0 + 2LL * GE2;         // 10,000,000  (ei2 end; a2 follows)

constexpr unsigned CHUNK = 400000;    // pse slots per XCD-chunk

// ---- ws layout (floats), 43.2 MB ----
constexpr size_t W_ESC  = 0;          // GE2 slot scalars
constexpr size_t W_XL1H = 3400000;    // N*HID bf16  (800k floats)
constexpr size_t W_XR1  = 4200000;    // N*HID f32
constexpr size_t W_XL2H = 5800000;    // N*OUT bf16  (1.6M floats)
constexpr size_t W_XR2  = 7400000;    // N*OUT f32
constexpr size_t W_RP   = 10600000;   // rowptr N+1 (int)
constexpr size_t W_CNT  = 10700004;   // cnt N (int)
constexpr size_t W_BS   = 10800004;   // scan block sums (256)
constexpr size_t W_SEA  = 10800260;
constexpr size_t W_WPI  = 10800261;
constexpr size_t W_END  = 10800264;

DEVFN int gidx(const int* __restrict__ ei, long long i, int wpi) {
    return ei[(size_t)i * (size_t)wpi];
}
DEVFN unsigned short f2b(float f) {               // f32 -> bf16 RNE
    unsigned u = __float_as_uint(f);
    unsigned r = ((u >> 16) & 1u) + 0x7fffu;
    return (unsigned short)((u + r) >> 16);
}
DEVFN float b2f(unsigned short h) {
    return __uint_as_float(((unsigned)h) << 16);
}

__global__ void gl_sentinel(float* outb) {        // ws too small -> Output 2 ~ 3840
    if (threadIdx.x == 0 && blockIdx.x == 0) outb[G1] = 3840.0f;
}

__global__ void gl_detect(const int* __restrict__ ei, int* flag) {
    int t = threadIdx.x;
    int v = ei[2 * t + 1];
    unsigned long long nz = __ballot(v != 0);
    if (t == 0) *flag = (nz == 0ull) ? 2 : 1;
}

__global__ void gl_sum(const float* __restrict__ p, int n, float* __restrict__ out) {
    float s = 0.f;
    for (int i = blockIdx.x * blockDim.x + threadIdx.x; i < n; i += gridDim.x * blockDim.x)
        s += p[i];
    #pragma unroll
    for (int o = 32; o > 0; o >>= 1) s += __shfl_down(s, o);
    __shared__ float ls[4];
    if ((threadIdx.x & 63) == 0) ls[threadIdx.x >> 6] = s;
    __syncthreads();
    if (threadIdx.x == 0) atomicAdd(out, ls[0] + ls[1] + ls[2] + ls[3]);
}

__global__ __launch_bounds__(256) void gl_projA(const float* __restrict__ x,
        const float* __restrict__ Wl, const float* __restrict__ Wr,
        unsigned short* __restrict__ xlh, float* __restrict__ xr) {
    __shared__ float sWl[GEMB * GHID], sWr[GEMB * GHID], sx[16 * GEMB];
    for (int i = threadIdx.x; i < GEMB * GHID; i += 256) { sWl[i] = Wl[i]; sWr[i] = Wr[i]; }
    int base = blockIdx.x * 16;
    for (int i = threadIdx.x; i < 16 * GEMB; i += 256) sx[i] = x[(size_t)base * GEMB + i];
    __syncthreads();
    int ln = threadIdx.x >> 4, ch = threadIdx.x & 15;
    float al = 0.f, ar = 0.f;
    #pragma unroll 8
    for (int k = 0; k < GEMB; ++k) {
        float xv = sx[ln * GEMB + k];
        al = fmaf(xv, sWl[k * GHID + ch], al);
        ar = fmaf(xv, sWr[k * GHID + ch], ar);
    }
    xlh[(size_t)(base + ln) * GHID + ch] = f2b(al);
    xr[(size_t)(base + ln) * GHID + ch] = ar;
}

__global__ __launch_bounds__(256) void gl_projB(const float* __restrict__ h,
        const float* __restrict__ Wl, const float* __restrict__ Wr,
        unsigned short* __restrict__ xlh, float* __restrict__ xr) {
    __shared__ float sWl[GHID * GOUT], sWr[GHID * GOUT], sx[8 * GHID];
    for (int i = threadIdx.x; i < GHID * GOUT; i += 256) { sWl[i] = Wl[i]; sWr[i] = Wr[i]; }
    int base = blockIdx.x * 8;
    for (int i = threadIdx.x; i < 8 * GHID; i += 256) sx[i] = h[(size_t)base * GHID + i];
    __syncthreads();
    int ln = threadIdx.x >> 5, ch = threadIdx.x & 31;
    float al = 0.f, ar = 0.f;
    #pragma unroll
    for (int k = 0; k < GHID; ++k) {
        float xv = sx[ln * GHID + k];
        al = fmaf(xv, sWl[k * GOUT + ch], al);
        ar = fmaf(xv, sWr[k * GOUT + ch], ar);
    }
    xlh[(size_t)(base + ln) * GOUT + ch] = f2b(al);
    xr[(size_t)(base + ln) * GOUT + ch] = ar;
}

// ---- hist: count per dst AND record (dst, local_rank) per edge ----
__global__ void gl_hist(const int* __restrict__ ei, const int* __restrict__ wpip,
                        int* __restrict__ cnt, int2* __restrict__ dl) {
    int e = blockIdx.x * blockDim.x + threadIdx.x;
    if (e >= GE) return;
    int wpi = *wpip;
    int dst = gidx(ei, (long long)GE + e, wpi);
    int lc = atomicAdd(&cnt[dst], 1);
    dl[e] = make_int2(dst, lc);
}

__global__ __launch_bounds__(1024) void gl_scan1(const int* __restrict__ cnt,
                                                 int* __restrict__ rp, int* __restrict__ bs) {
    __shared__ int s[1024];
    int t = threadIdx.x, u = blockIdx.x * 1024 + t;
    s[t] = (u < GN) ? cnt[u] : 0;
    __syncthreads();
    for (int off = 1; off < 1024; off <<= 1) {
        int a = (t >= off) ? s[t - off] : 0;
        __syncthreads();
        s[t] += a;
        __syncthreads();
    }
    if (u < GN) rp[u + 1] = s[t];
    if (t == 1023) bs[blockIdx.x] = s[1023];
}
__global__ void gl_scan2(int* __restrict__ bs, int nb) {
    __shared__ int s[128];
    int t = threadIdx.x;
    s[t] = (t < nb) ? bs[t] : 0;
    __syncthreads();
    for (int off = 1; off < 128; off <<= 1) {
        int a = (t >= off) ? s[t - off] : 0;
        __syncthreads();
        s[t] += a;
        __syncthreads();
    }
    if (t < nb) bs[t] = (t == 0) ? 0 : s[t - 1];
}
__global__ void gl_scan3(int* __restrict__ rp, const int* __restrict__ bs) {
    int u = blockIdx.x * blockDim.x + threadIdx.x;
    if (u < GN) rp[u + 1] += bs[u >> 10];
    if (u == 0) rp[0] = 0;
}

__global__ void gl_slots(const int2* __restrict__ dl, const int* __restrict__ rp,
                         int* __restrict__ inv) {
    int e = blockIdx.x * blockDim.x + threadIdx.x;
    if (e >= GE) return;
    int2 d = dl[e];
    inv[e] = rp[d.x] + d.y;
}

// ---- scatter: chunk-per-XCD (full-line writeback) ----
__global__ __launch_bounds__(256) void gl_scatter(const int* __restrict__ ei,
        const int* __restrict__ wpip, const float* __restrict__ eattr,
        const int* __restrict__ inv, int2* __restrict__ pse) {
    int wpi = *wpip;
    unsigned ck = blockIdx.x & 7;
    int stride = (gridDim.x >> 3) * 256;
    for (int e = (blockIdx.x >> 3) * 256 + threadIdx.x; e < GE; e += stride) {
        int slot = inv[e];
        if ((unsigned)slot / CHUNK == ck) {
            int src = gidx(ei, e, wpi);
            pse[slot] = make_int2(src, __float_as_int(eattr[e]));
        }
    }
}

// ------------- fused layer 1: online softmax, bf16 gathers (HID=16) -------------
__global__ __launch_bounds__(256) void gl_L1(const int* __restrict__ rp,
        const int2* __restrict__ pse, const float* __restrict__ sea,
        const unsigned short* __restrict__ xlh, const float* __restrict__ xr,
        const float* __restrict__ We, const float* __restrict__ att,
        const float* __restrict__ b1, float* __restrict__ esc,
        float* __restrict__ h1) {
    int u = blockIdx.x * 4 + (threadIdx.x >> 6);
    int lane = threadIdx.x & 63, sub = lane >> 4, ch = lane & 15;
    int beg = rp[u], end = rp[u + 1];
    float we = We[ch], at = att[ch];
    float xru = xr[(size_t)u * GHID + ch];
    float mx = -3.0e38f, pd = 0.f, acc = 0.f;
    for (int i = beg + sub; i < end; i += 4) {
        int2 p = pse[i];
        float xls = b2f(xlh[(size_t)p.x * GHID + ch]);
        float v = xls + xru + __int_as_float(p.y) * we;
        v = v > 0.f ? v : GNEG * v;
        float lg = v * at;
        lg += __shfl_xor(lg, 1); lg += __shfl_xor(lg, 2);
        lg += __shfl_xor(lg, 4); lg += __shfl_xor(lg, 8);
        if (ch == 0) esc[i] = lg;
        float nm = fmaxf(mx, lg);
        float sc = __expf(mx - nm), pp = __expf(lg - nm);
        pd = pd * sc + pp;
        acc = acc * sc + pp * xls;
        mx = nm;
    }
    float lgself = 0.f;
    if (sub == 0) {                                 // self-loop (ea = mean(edge_attr))
        float xls = b2f(xlh[(size_t)u * GHID + ch]);
        float v = xls + xru + (sea[0] * (1.f / (float)GE)) * we;
        v = v > 0.f ? v : GNEG * v;
        float lg = v * at;
        lg += __shfl_xor(lg, 1); lg += __shfl_xor(lg, 2);
        lg += __shfl_xor(lg, 4); lg += __shfl_xor(lg, 8);
        lgself = lg;
        float nm = fmaxf(mx, lg);
        float sc = __expf(mx - nm), pp = __expf(lg - nm);
        pd = pd * sc + pp;
        acc = acc * sc + pp * xls;
        mx = nm;
    }
    #pragma unroll
    for (int o = 16; o <= 32; o <<= 1) {            // merge 4 subgroups
        float mo = __shfl_xor(mx, o), po = __shfl_xor(pd, o), ao = __shfl_xor(acc, o);
        float nm = fmaxf(mx, mo);
        float sa = __expf(mx - nm), sb = __expf(mo - nm);
        pd = pd * sa + po * sb;
        acc = acc * sa + ao * sb;
        mx = nm;
    }
    float dinv = 1.f / pd;
    __threadfence_block();
    for (int i = beg + lane; i < end; i += 64)      // alpha pass (coalesced)
        esc[i] = __expf(esc[i] - mx) * dinv;
    if (lane == 0) esc[GE + u] = __expf(lgself - mx) * dinv;
    if (lane < 16) {
        float o = acc * dinv + b1[ch];
        h1[(size_t)u * GHID + ch] = o > 0.f ? o : 0.f;   // fused bias+relu
    }
}

// ------------- fused layer 2: online softmax, bf16 gathers (OUT=32) -------------
__global__ __launch_bounds__(256) void gl_L2(const int* __restrict__ rp,
        const int2* __restrict__ pse,
        const unsigned short* __restrict__ xlh, const float* __restrict__ xr,
        const float* __restrict__ We, const float* __restrict__ att,
        const float* __restrict__ b2, float* __restrict__ esc,
        float* __restrict__ out0) {
    int u = blockIdx.x * 4 + (threadIdx.x >> 6);
    int lane = threadIdx.x & 63, sub = lane >> 5, ch = lane & 31;
    int beg = rp[u], end = rp[u + 1];
    float we = We[ch], at = att[ch];
    float xru = xr[(size_t)u * GOUT + ch];
    float mx = -3.0e38f, pd = 0.f, acc = 0.f;
    for (int i = beg + sub; i < end; i += 2) {
        float ea = esc[i];                          // alpha1 (slot order)
        float xls = b2f(xlh[(size_t)pse[i].x * GOUT + ch]);
        float v = xls + xru + ea * we;
        v = v > 0.f ? v : GNEG * v;
        float lg = v * at;
        lg += __shfl_xor(lg, 1); lg += __shfl_xor(lg, 2); lg += __shfl_xor(lg, 4);
        lg += __shfl_xor(lg, 8); lg += __shfl_xor(lg, 16);
        if (ch == 0) esc[i] = lg;
        float nm = fmaxf(mx, lg);
        float sc = __expf(mx - nm), pp = __expf(lg - nm);
        pd = pd * sc + pp;
        acc = acc * sc + pp * xls;
        mx = nm;
    }
    float lgs;
    {   // two self-loops: sub0 -> ea=alpha1_self, sub1 -> ea=mean(alpha1)=N/E1
        float ea = (sub == 0) ? esc[GE + u] : GEA2;
        float xls = b2f(xlh[(size_t)u * GOUT + ch]);
        float v = xls + xru + ea * we;
        v = v > 0.f ? v : GNEG * v;
        float lg = v * at;
        lg += __shfl_xor(lg, 1); lg += __shfl_xor(lg, 2); lg += __shfl_xor(lg, 4);
        lg += __shfl_xor(lg, 8); lg += __shfl_xor(lg, 16);
        lgs = lg;
        float nm = fmaxf(mx, lg);
        float sc = __expf(mx - nm), pp = __expf(lg - nm);
        pd = pd * sc + pp;
        acc = acc * sc + pp * xls;
        mx = nm;
    }
    {   // merge 2 subgroups
        float mo = __shfl_xor(mx, 32), po = __shfl_xor(pd, 32), ao = __shfl_xor(acc, 32);
        float nm = fmaxf(mx, mo);
        float sa = __expf(mx - nm), sb = __expf(mo - nm);
        pd = pd * sa + po * sb;
        acc = acc * sa + ao * sb;
        mx = nm;
    }
    float dinv = 1.f / pd;
    __threadfence_block();
    for (int i = beg + lane; i < end; i += 64)      // alpha2 pass (coalesced)
        esc[i] = __expf(esc[i] - mx) * dinv;
    if (lane == 0)  esc[GE + u]  = __expf(lgs - mx) * dinv;
    if (lane == 32) esc[GE1 + u] = __expf(lgs - mx) * dinv;
    if (lane < 32) out0[(size_t)u * GOUT + ch] = acc * dinv + b2[ch];
}

// fused epilogue: ei2 (2 floats) + a2 (1 float) per index, one pass.
__global__ void gl_ep(const int* __restrict__ ei, const int* __restrict__ wpip,
                      const int* __restrict__ inv, const float* __restrict__ esc,
                      float* __restrict__ outb) {
    int c = blockIdx.x * blockDim.x + threadIdx.x;
    if (c >= GE2) return;
    int wpi = *wpip;
    int s, dd;
    float av;
    if (c < GE) {
        s = gidx(ei, c, wpi);
        dd = gidx(ei, (long long)GE + c, wpi);
        av = esc[inv[c]];
    } else if (c < GE1) {
        s = dd = c - GE;
        av = esc[c];
    } else {
        s = dd = c - GE1;
        av = esc[c];
    }
    outb[G0 + c]       = (float)s;
    outb[G0 + GE2 + c] = (float)dd;
    outb[G1 + c]       = av;
}

extern "C" void kernel_launch(void* const* d_in, const int* in_sizes, int n_in,
                              void* d_out, int out_size, void* d_ws, size_t ws_size,
                              hipStream_t stream) {
    const float* x     = (const float*)d_in[0];
    const int*   ei    = (const int*)d_in[1];
    const float* eattr = (const float*)d_in[2];
    const float* W1l   = (const float*)d_in[3];
    const float* W1r   = (const float*)d_in[4];
    const float* W1e   = (const float*)d_in[5];
    const float* att1  = (const float*)d_in[6];
    const float* b1    = (const float*)d_in[7];
    const float* W2l   = (const float*)d_in[8];
    const float* W2r   = (const float*)d_in[9];
    const float* W2e   = (const float*)d_in[10];
    const float* att2  = (const float*)d_in[11];
    const float* b2    = (const float*)d_in[12];
    float* outf = (float*)d_out;

    float* ws = (float*)d_ws;
    if (W_END * sizeof(float) > ws_size) {          // 43.2 MB needed
        gl_sentinel<<<1, 64, 0, stream>>>(outf);
        return;
    }

    float*          esc  = ws + W_ESC;
    unsigned short* xl1h = (unsigned short*)(ws + W_XL1H);
    float*          xr1  = ws + W_XR1;
    unsigned short* xl2h = (unsigned short*)(ws + W_XL2H);
    float*          xr2  = ws + W_XR2;
    int*            rp   = (int*)(ws + W_RP);
    int*            cnt  = (int*)(ws + W_CNT);
    int*            bs   = (int*)(ws + W_BS);
    float*          sea  = ws + W_SEA;
    int*            wpi  = (int*)(ws + W_WPI);

    // d_out scratch (each dead before its region's final writer):
    int2*  dl  = (int2*)(outf + G0);                // ei2 region; dead after gl_slots
    int2*  pse = (int2*)(outf + G0);                // same region, rewritten by gl_scatter
    int*   inv = (int*)(outf + G1);                 // a2 region, read-then-overwritten by gl_ep
    float* h1  = outf;                              // chunk0, killed by L2's out0

    hipMemsetAsync(cnt, 0, GN * sizeof(int), stream);
    hipMemsetAsync(sea, 0, 2 * sizeof(float), stream);

    gl_detect<<<1, 64, 0, stream>>>(ei, wpi);
    gl_sum<<<1024, 256, 0, stream>>>(eattr, GE, sea);
    gl_projA<<<GN / 16, 256, 0, stream>>>(x, W1l, W1r, xl1h, xr1);

    int nbe = (GE + 255) / 256;
    gl_hist<<<nbe, 256, 0, stream>>>(ei, wpi, cnt, dl);
    gl_scan1<<<(GN + 1023) / 1024, 1024, 0, stream>>>(cnt, rp, bs);
    gl_scan2<<<1, 128, 0, stream>>>(bs, (GN + 1023) / 1024);
    gl_scan3<<<(GN + 255) / 256, 256, 0, stream>>>(rp, bs);
    gl_slots<<<nbe, 256, 0, stream>>>(dl, rp, inv);
    gl_scatter<<<8192, 256, 0, stream>>>(ei, wpi, eattr, inv, pse);

    gl_L1<<<GN / 4, 256, 0, stream>>>(rp, pse, sea, xl1h, xr1, W1e, att1, b1, esc, h1);
    gl_projB<<<GN / 8, 256, 0, stream>>>(h1, W2l, W2r, xl2h, xr2);
    gl_L2<<<GN / 4, 256, 0, stream>>>(rp, pse, xl2h, xr2, W2e, att2, b2, esc, outf);
    gl_ep<<<(GE2 + 255) / 256, 256, 0, stream>>>(ei, wpi, inv, esc, outf);
}

// Round 18
// 524.196 us; speedup vs baseline: 1.3692x; 1.3692x over previous
//
#include <hip/hip_runtime.h>

#define DEVFN __device__ __forceinline__

constexpr int GN = 100000, GE = 3200000;
constexpr int GE1 = GE + GN;          // 3,300,000
constexpr int GE2 = GE1 + GN;         // 3,400,000
constexpr int GEMB = 128, GHID = 16, GOUT = 32;
constexpr float GNEG = 0.2f;
constexpr float GEA2 = 100000.f / 3300000.f;   // mean(alpha1) = N/E1 exactly

constexpr long long G0 = (long long)GN * GOUT;   //  3,200,000  (out end)
constexpr long long G1 = G0 + 2LL * GE2;         // 10,000,000  (ei2 end; a2 follows)

constexpr unsigned CHUNK = 400000;    // pse slots per XCD-chunk

// ---- ws layout (floats), 43.2 MB ----
constexpr size_t W_ESC  = 0;          // GE2 slot scalars
constexpr size_t W_XL1H = 3400000;    // N*HID bf16
constexpr size_t W_XR1  = 4200000;    // N*HID f32
constexpr size_t W_XL2H = 5800000;    // N*OUT bf16
constexpr size_t W_XR2  = 7400000;    // N*OUT f32
constexpr size_t W_RP   = 10600000;   // rowptr N+1 (int)
constexpr size_t W_CNT  = 10700004;   // cnt N (int)
constexpr size_t W_BS   = 10800004;   // scan block sums (256)
constexpr size_t W_SEA  = 10800260;
constexpr size_t W_WPI  = 10800261;
constexpr size_t W_END  = 10800264;

DEVFN int gidx(const int* __restrict__ ei, long long i, int wpi) {
    return ei[(size_t)i * (size_t)wpi];
}
DEVFN unsigned short f2b(float f) {               // f32 -> bf16 RNE
    unsigned u = __float_as_uint(f);
    unsigned r = ((u >> 16) & 1u) + 0x7fffu;
    return (unsigned short)((u + r) >> 16);
}
DEVFN float b2fl(unsigned u) { return __uint_as_float(u << 16); }
DEVFN float b2fh(unsigned u) { return __uint_as_float(u & 0xffff0000u); }

__global__ void gl_sentinel(float* outb) {        // ws too small -> Output 2 ~ 3840
    if (threadIdx.x == 0 && blockIdx.x == 0) outb[G1] = 3840.0f;
}

__global__ void gl_detect(const int* __restrict__ ei, int* flag) {
    int t = threadIdx.x;
    int v = ei[2 * t + 1];
    unsigned long long nz = __ballot(v != 0);
    if (t == 0) *flag = (nz == 0ull) ? 2 : 1;
}

__global__ void gl_sum(const float* __restrict__ p, int n, float* __restrict__ out) {
    float s = 0.f;
    for (int i = blockIdx.x * blockDim.x + threadIdx.x; i < n; i += gridDim.x * blockDim.x)
        s += p[i];
    #pragma unroll
    for (int o = 32; o > 0; o >>= 1) s += __shfl_down(s, o);
    __shared__ float ls[4];
    if ((threadIdx.x & 63) == 0) ls[threadIdx.x >> 6] = s;
    __syncthreads();
    if (threadIdx.x == 0) atomicAdd(out, ls[0] + ls[1] + ls[2] + ls[3]);
}

__global__ __launch_bounds__(256) void gl_projA(const float* __restrict__ x,
        const float* __restrict__ Wl, const float* __restrict__ Wr,
        unsigned short* __restrict__ xlh, float* __restrict__ xr) {
    __shared__ float sWl[GEMB * GHID], sWr[GEMB * GHID], sx[16 * GEMB];
    for (int i = threadIdx.x; i < GEMB * GHID; i += 256) { sWl[i] = Wl[i]; sWr[i] = Wr[i]; }
    int base = blockIdx.x * 16;
    for (int i = threadIdx.x; i < 16 * GEMB; i += 256) sx[i] = x[(size_t)base * GEMB + i];
    __syncthreads();
    int ln = threadIdx.x >> 4, ch = threadIdx.x & 15;
    float al = 0.f, ar = 0.f;
    #pragma unroll 8
    for (int k = 0; k < GEMB; ++k) {
        float xv = sx[ln * GEMB + k];
        al = fmaf(xv, sWl[k * GHID + ch], al);
        ar = fmaf(xv, sWr[k * GHID + ch], ar);
    }
    xlh[(size_t)(base + ln) * GHID + ch] = f2b(al);
    xr[(size_t)(base + ln) * GHID + ch] = ar;
}

__global__ __launch_bounds__(256) void gl_projB(const float* __restrict__ h,
        const float* __restrict__ Wl, const float* __restrict__ Wr,
        unsigned short* __restrict__ xlh, float* __restrict__ xr) {
    __shared__ float sWl[GHID * GOUT], sWr[GHID * GOUT], sx[8 * GHID];
    for (int i = threadIdx.x; i < GHID * GOUT; i += 256) { sWl[i] = Wl[i]; sWr[i] = Wr[i]; }
    int base = blockIdx.x * 8;
    for (int i = threadIdx.x; i < 8 * GHID; i += 256) sx[i] = h[(size_t)base * GHID + i];
    __syncthreads();
    int ln = threadIdx.x >> 5, ch = threadIdx.x & 31;
    float al = 0.f, ar = 0.f;
    #pragma unroll
    for (int k = 0; k < GHID; ++k) {
        float xv = sx[ln * GHID + k];
        al = fmaf(xv, sWl[k * GOUT + ch], al);
        ar = fmaf(xv, sWr[k * GOUT + ch], ar);
    }
    xlh[(size_t)(base + ln) * GOUT + ch] = f2b(al);
    xr[(size_t)(base + ln) * GOUT + ch] = ar;
}

// ---- hist: count per dst AND record (dst, local_rank) per edge ----
__global__ void gl_hist(const int* __restrict__ ei, const int* __restrict__ wpip,
                        int* __restrict__ cnt, int2* __restrict__ dl) {
    int e = blockIdx.x * blockDim.x + threadIdx.x;
    if (e >= GE) return;
    int wpi = *wpip;
    int dst = gidx(ei, (long long)GE + e, wpi);
    int lc = atomicAdd(&cnt[dst], 1);
    dl[e] = make_int2(dst, lc);
}

__global__ __launch_bounds__(1024) void gl_scan1(const int* __restrict__ cnt,
                                                 int* __restrict__ rp, int* __restrict__ bs) {
    __shared__ int s[1024];
    int t = threadIdx.x, u = blockIdx.x * 1024 + t;
    s[t] = (u < GN) ? cnt[u] : 0;
    __syncthreads();
    for (int off = 1; off < 1024; off <<= 1) {
        int a = (t >= off) ? s[t - off] : 0;
        __syncthreads();
        s[t] += a;
        __syncthreads();
    }
    if (u < GN) rp[u + 1] = s[t];
    if (t == 1023) bs[blockIdx.x] = s[1023];
}
__global__ void gl_scan2(int* __restrict__ bs, int nb) {
    __shared__ int s[128];
    int t = threadIdx.x;
    s[t] = (t < nb) ? bs[t] : 0;
    __syncthreads();
    for (int off = 1; off < 128; off <<= 1) {
        int a = (t >= off) ? s[t - off] : 0;
        __syncthreads();
        s[t] += a;
        __syncthreads();
    }
    if (t < nb) bs[t] = (t == 0) ? 0 : s[t - 1];
}
__global__ void gl_scan3(int* __restrict__ rp, const int* __restrict__ bs) {
    int u = blockIdx.x * blockDim.x + threadIdx.x;
    if (u < GN) rp[u + 1] += bs[u >> 10];
    if (u == 0) rp[0] = 0;
}

__global__ void gl_slots(const int2* __restrict__ dl, const int* __restrict__ rp,
                         int* __restrict__ inv) {
    int e = blockIdx.x * blockDim.x + threadIdx.x;
    if (e >= GE) return;
    int2 d = dl[e];
    inv[e] = rp[d.x] + d.y;
}

// ---- scatter: chunk-per-XCD (full-line writeback) ----
__global__ __launch_bounds__(256) void gl_scatter(const int* __restrict__ ei,
        const int* __restrict__ wpip, const float* __restrict__ eattr,
        const int* __restrict__ inv, int2* __restrict__ pse) {
    int wpi = *wpip;
    unsigned ck = blockIdx.x & 7;
    int stride = (gridDim.x >> 3) * 256;
    for (int e = (blockIdx.x >> 3) * 256 + threadIdx.x; e < GE; e += stride) {
        int slot = inv[e];
        if ((unsigned)slot / CHUNK == ck) {
            int src = gidx(ei, e, wpi);
            pse[slot] = make_int2(src, __float_as_int(eattr[e]));
        }
    }
}

// ------- fused layer 1: 4 lanes/edge, 16 edges in flight/wave (HID=16) -------
__global__ __launch_bounds__(256) void gl_L1(const int* __restrict__ rp,
        const int2* __restrict__ pse, const float* __restrict__ sea,
        const unsigned short* __restrict__ xlh, const float* __restrict__ xr,
        const float* __restrict__ We, const float* __restrict__ att,
        const float* __restrict__ b1, float* __restrict__ esc,
        float* __restrict__ h1) {
    int u = blockIdx.x * 4 + (threadIdx.x >> 6);
    int lane = threadIdx.x & 63, sg = lane >> 2, ln4 = lane & 3;
    int beg = rp[u], end = rp[u + 1];
    float4 we = *(const float4*)(We + ln4 * 4);
    float4 at = *(const float4*)(att + ln4 * 4);
    float4 xru = *(const float4*)(xr + (size_t)u * GHID + ln4 * 4);
    float mx = -3.0e38f, pd = 0.f;
    float4 acc = make_float4(0.f, 0.f, 0.f, 0.f);
    for (int i = beg + sg; i < end; i += 16) {
        int2 p = pse[i];
        uint2 h = *(const uint2*)(xlh + (size_t)p.x * GHID + ln4 * 4);
        float ea = __int_as_float(p.y);
        float x0 = b2fl(h.x), x1 = b2fh(h.x), x2 = b2fl(h.y), x3 = b2fh(h.y);
        float v, s = 0.f;
        v = x0 + xru.x + ea * we.x; v = v > 0.f ? v : GNEG * v; s = fmaf(v, at.x, s);
        v = x1 + xru.y + ea * we.y; v = v > 0.f ? v : GNEG * v; s = fmaf(v, at.y, s);
        v = x2 + xru.z + ea * we.z; v = v > 0.f ? v : GNEG * v; s = fmaf(v, at.z, s);
        v = x3 + xru.w + ea * we.w; v = v > 0.f ? v : GNEG * v; s = fmaf(v, at.w, s);
        s += __shfl_xor(s, 1); s += __shfl_xor(s, 2);
        if (ln4 == 0) esc[i] = s;
        float nm = fmaxf(mx, s);
        float sc = __expf(mx - nm), pp = __expf(s - nm);
        pd = pd * sc + pp;
        acc.x = acc.x * sc + pp * x0; acc.y = acc.y * sc + pp * x1;
        acc.z = acc.z * sc + pp * x2; acc.w = acc.w * sc + pp * x3;
        mx = nm;
    }
    float lgself = 0.f;
    if (sg == 0) {                                  // self-loop (ea = mean(edge_attr))
        uint2 h = *(const uint2*)(xlh + (size_t)u * GHID + ln4 * 4);
        float ea = sea[0] * (1.f / (float)GE);
        float x0 = b2fl(h.x), x1 = b2fh(h.x), x2 = b2fl(h.y), x3 = b2fh(h.y);
        float v, s = 0.f;
        v = x0 + xru.x + ea * we.x; v = v > 0.f ? v : GNEG * v; s = fmaf(v, at.x, s);
        v = x1 + xru.y + ea * we.y; v = v > 0.f ? v : GNEG * v; s = fmaf(v, at.y, s);
        v = x2 + xru.z + ea * we.z; v = v > 0.f ? v : GNEG * v; s = fmaf(v, at.z, s);
        v = x3 + xru.w + ea * we.w; v = v > 0.f ? v : GNEG * v; s = fmaf(v, at.w, s);
        s += __shfl_xor(s, 1); s += __shfl_xor(s, 2);
        lgself = s;
        float nm = fmaxf(mx, s);
        float sc = __expf(mx - nm), pp = __expf(s - nm);
        pd = pd * sc + pp;
        acc.x = acc.x * sc + pp * x0; acc.y = acc.y * sc + pp * x1;
        acc.z = acc.z * sc + pp * x2; acc.w = acc.w * sc + pp * x3;
        mx = nm;
    }
    #pragma unroll
    for (int o = 4; o <= 32; o <<= 1) {             // merge 16 subgroups
        float mo = __shfl_xor(mx, o), po = __shfl_xor(pd, o);
        float a0 = __shfl_xor(acc.x, o), a1 = __shfl_xor(acc.y, o);
        float a2 = __shfl_xor(acc.z, o), a3 = __shfl_xor(acc.w, o);
        float nm = fmaxf(mx, mo);
        float sa = __expf(mx - nm), sb = __expf(mo - nm);
        pd = pd * sa + po * sb;
        acc.x = acc.x * sa + a0 * sb; acc.y = acc.y * sa + a1 * sb;
        acc.z = acc.z * sa + a2 * sb; acc.w = acc.w * sa + a3 * sb;
        mx = nm;
    }
    float dinv = 1.f / pd;
    __threadfence_block();
    for (int i = beg + lane; i < end; i += 64)      // alpha pass (coalesced)
        esc[i] = __expf(esc[i] - mx) * dinv;
    if (lane == 0) esc[GE + u] = __expf(lgself - mx) * dinv;
    if (lane < 4) {
        float4 b = *(const float4*)(b1 + lane * 4);
        float4 o;
        o.x = acc.x * dinv + b.x; o.y = acc.y * dinv + b.y;
        o.z = acc.z * dinv + b.z; o.w = acc.w * dinv + b.w;
        o.x = o.x > 0.f ? o.x : 0.f; o.y = o.y > 0.f ? o.y : 0.f;
        o.z = o.z > 0.f ? o.z : 0.f; o.w = o.w > 0.f ? o.w : 0.f;
        *(float4*)(h1 + (size_t)u * GHID + lane * 4) = o;   // fused bias+relu
    }
}

// ------- fused layer 2: 8 lanes/edge, 8 edges in flight/wave (OUT=32) -------
__global__ __launch_bounds__(256) void gl_L2(const int* __restrict__ rp,
        const int2* __restrict__ pse,
        const unsigned short* __restrict__ xlh, const float* __restrict__ xr,
        const float* __restrict__ We, const float* __restrict__ att,
        const float* __restrict__ b2, float* __restrict__ esc,
        float* __restrict__ out0) {
    int u = blockIdx.x * 4 + (threadIdx.x >> 6);
    int lane = threadIdx.x & 63, sg = lane >> 3, ln8 = lane & 7;
    int beg = rp[u], end = rp[u + 1];
    float4 we = *(const float4*)(We + ln8 * 4);
    float4 at = *(const float4*)(att + ln8 * 4);
    float4 xru = *(const float4*)(xr + (size_t)u * GOUT + ln8 * 4);
    float mx = -3.0e38f, pd = 0.f;
    float4 acc = make_float4(0.f, 0.f, 0.f, 0.f);
    for (int i = beg + sg; i < end; i += 8) {
        int2 p = pse[i];
        float ea = esc[i];                          // alpha1 (slot order)
        uint2 h = *(const uint2*)(xlh + (size_t)p.x * GOUT + ln8 * 4);
        float x0 = b2fl(h.x), x1 = b2fh(h.x), x2 = b2fl(h.y), x3 = b2fh(h.y);
        float v, s = 0.f;
        v = x0 + xru.x + ea * we.x; v = v > 0.f ? v : GNEG * v; s = fmaf(v, at.x, s);
        v = x1 + xru.y + ea * we.y; v = v > 0.f ? v : GNEG * v; s = fmaf(v, at.y, s);
        v = x2 + xru.z + ea * we.z; v = v > 0.f ? v : GNEG * v; s = fmaf(v, at.z, s);
        v = x3 + xru.w + ea * we.w; v = v > 0.f ? v : GNEG * v; s = fmaf(v, at.w, s);
        s += __shfl_xor(s, 1); s += __shfl_xor(s, 2); s += __shfl_xor(s, 4);
        if (ln8 == 0) esc[i] = s;
        float nm = fmaxf(mx, s);
        float sc = __expf(mx - nm), pp = __expf(s - nm);
        pd = pd * sc + pp;
        acc.x = acc.x * sc + pp * x0; acc.y = acc.y * sc + pp * x1;
        acc.z = acc.z * sc + pp * x2; acc.w = acc.w * sc + pp * x3;
        mx = nm;
    }
    float lgs = 0.f;
    if (sg < 2) {   // two self-loops: sg0 -> ea=alpha1_self, sg1 -> ea=N/E1
        float ea = (sg == 0) ? esc[GE + u] : GEA2;
        uint2 h = *(const uint2*)(xlh + (size_t)u * GOUT + ln8 * 4);
        float x0 = b2fl(h.x), x1 = b2fh(h.x), x2 = b2fl(h.y), x3 = b2fh(h.y);
        float v, s = 0.f;
        v = x0 + xru.x + ea * we.x; v = v > 0.f ? v : GNEG * v; s = fmaf(v, at.x, s);
        v = x1 + xru.y + ea * we.y; v = v > 0.f ? v : GNEG * v; s = fmaf(v, at.y, s);
        v = x2 + xru.z + ea * we.z; v = v > 0.f ? v : GNEG * v; s = fmaf(v, at.z, s);
        v = x3 + xru.w + ea * we.w; v = v > 0.f ? v : GNEG * v; s = fmaf(v, at.w, s);
        s += __shfl_xor(s, 1); s += __shfl_xor(s, 2); s += __shfl_xor(s, 4);
        lgs = s;
        float nm = fmaxf(mx, s);
        float sc = __expf(mx - nm), pp = __expf(s - nm);
        pd = pd * sc + pp;
        acc.x = acc.x * sc + pp * x0; acc.y = acc.y * sc + pp * x1;
        acc.z = acc.z * sc + pp * x2; acc.w = acc.w * sc + pp * x3;
        mx = nm;
    }
    #pragma unroll
    for (int o = 8; o <= 32; o <<= 1) {             // merge 8 subgroups
        float mo = __shfl_xor(mx, o), po = __shfl_xor(pd, o);
        float a0 = __shfl_xor(acc.x, o), a1 = __shfl_xor(acc.y, o);
        float a2 = __shfl_xor(acc.z, o), a3 = __shfl_xor(acc.w, o);
        float nm = fmaxf(mx, mo);
        float sa = __expf(mx - nm), sb = __expf(mo - nm);
        pd = pd * sa + po * sb;
        acc.x = acc.x * sa + a0 * sb; acc.y = acc.y * sa + a1 * sb;
        acc.z = acc.z * sa + a2 * sb; acc.w = acc.w * sa + a3 * sb;
        mx = nm;
    }
    float dinv = 1.f / pd;
    __threadfence_block();
    for (int i = beg + lane; i < end; i += 64)      // alpha2 pass (coalesced)
        esc[i] = __expf(esc[i] - mx) * dinv;
    if (lane == 0) esc[GE + u]  = __expf(lgs - mx) * dinv;
    if (lane == 8) esc[GE1 + u] = __expf(lgs - mx) * dinv;
    if (lane < 8) {
        float4 b = *(const float4*)(b2 + lane * 4);
        float4 o;
        o.x = acc.x * dinv + b.x; o.y = acc.y * dinv + b.y;
        o.z = acc.z * dinv + b.z; o.w = acc.w * dinv + b.w;
        *(float4*)(out0 + (size_t)u * GOUT + lane * 4) = o;
    }
}

// fused epilogue: ei2 (2 floats) + a2 (1 float) per index, one pass.
__global__ void gl_ep(const int* __restrict__ ei, const int* __restrict__ wpip,
                      const int* __restrict__ inv, const float* __restrict__ esc,
                      float* __restrict__ outb) {
    int c = blockIdx.x * blockDim.x + threadIdx.x;
    if (c >= GE2) return;
    int wpi = *wpip;
    int s, dd;
    float av;
    if (c < GE) {
        s = gidx(ei, c, wpi);
        dd = gidx(ei, (long long)GE + c, wpi);
        av = esc[inv[c]];
    } else if (c < GE1) {
        s = dd = c - GE;
        av = esc[c];
    } else {
        s = dd = c - GE1;
        av = esc[c];
    }
    outb[G0 + c]       = (float)s;
    outb[G0 + GE2 + c] = (float)dd;
    outb[G1 + c]       = av;
}

extern "C" void kernel_launch(void* const* d_in, const int* in_sizes, int n_in,
                              void* d_out, int out_size, void* d_ws, size_t ws_size,
                              hipStream_t stream) {
    const float* x     = (const float*)d_in[0];
    const int*   ei    = (const int*)d_in[1];
    const float* eattr = (const float*)d_in[2];
    const float* W1l   = (const float*)d_in[3];
    const float* W1r   = (const float*)d_in[4];
    const float* W1e   = (const float*)d_in[5];
    const float* att1  = (const float*)d_in[6];
    const float* b1    = (const float*)d_in[7];
    const float* W2l   = (const float*)d_in[8];
    const float* W2r   = (const float*)d_in[9];
    const float* W2e   = (const float*)d_in[10];
    const float* att2  = (const float*)d_in[11];
    const float* b2    = (const float*)d_in[12];
    float* outf = (float*)d_out;

    float* ws = (float*)d_ws;
    if (W_END * sizeof(float) > ws_size) {          // 43.2 MB needed
        gl_sentinel<<<1, 64, 0, stream>>>(outf);
        return;
    }

    float*          esc  = ws + W_ESC;
    unsigned short* xl1h = (unsigned short*)(ws + W_XL1H);
    float*          xr1  = ws + W_XR1;
    unsigned short* xl2h = (unsigned short*)(ws + W_XL2H);
    float*          xr2  = ws + W_XR2;
    int*            rp   = (int*)(ws + W_RP);
    int*            cnt  = (int*)(ws + W_CNT);
    int*            bs   = (int*)(ws + W_BS);
    float*          sea  = ws + W_SEA;
    int*            wpi  = (int*)(ws + W_WPI);

    // d_out scratch (each dead before its region's final writer):
    int2*  dl  = (int2*)(outf + G0);                // ei2 region; dead after gl_slots
    int2*  pse = (int2*)(outf + G0);                // same region, rewritten by gl_scatter
    int*   inv = (int*)(outf + G1);                 // a2 region, read-then-overwritten by gl_ep
    float* h1  = outf;                              // chunk0, killed by L2's out0

    hipMemsetAsync(cnt, 0, GN * sizeof(int), stream);
    hipMemsetAsync(sea, 0, 2 * sizeof(float), stream);

    gl_detect<<<1, 64, 0, stream>>>(ei, wpi);
    gl_sum<<<1024, 256, 0, stream>>>(eattr, GE, sea);
    gl_projA<<<GN / 16, 256, 0, stream>>>(x, W1l, W1r, xl1h, xr1);

    int nbe = (GE + 255) / 256;
    gl_hist<<<nbe, 256, 0, stream>>>(ei, wpi, cnt, dl);
    gl_scan1<<<(GN + 1023) / 1024, 1024, 0, stream>>>(cnt, rp, bs);
    gl_scan2<<<1, 128, 0, stream>>>(bs, (GN + 1023) / 1024);
    gl_scan3<<<(GN + 255) / 256, 256, 0, stream>>>(rp, bs);
    gl_slots<<<nbe, 256, 0, stream>>>(dl, rp, inv);
    gl_scatter<<<8192, 256, 0, stream>>>(ei, wpi, eattr, inv, pse);

    gl_L1<<<GN / 4, 256, 0, stream>>>(rp, pse, sea, xl1h, xr1, W1e, att1, b1, esc, h1);
    gl_projB<<<GN / 8, 256, 0, stream>>>(h1, W2l, W2r, xl2h, xr2);
    gl_L2<<<GN / 4, 256, 0, stream>>>(rp, pse, xl2h, xr2, W2e, att2, b2, esc, outf);
    gl_ep<<<(GE2 + 255) / 256, 256, 0, stream>>>(ei, wpi, inv, esc, outf);
}

// Round 20
// 516.622 us; speedup vs baseline: 1.3893x; 1.0147x over previous
//
#include <hip/hip_runtime.h>

#define DEVFN __device__ __forceinline__

constexpr int GN = 100000, GE = 3200000;
constexpr int GE1 = GE + GN;          // 3,300,000
constexpr int GE2 = GE1 + GN;         // 3,400,000
constexpr int GEMB = 128, GHID = 16, GOUT = 32;
constexpr float GNEG = 0.2f;
constexpr float GEA2 = 100000.f / 3300000.f;   // mean(alpha1) = N/E1 exactly

constexpr long long G0 = (long long)GN * GOUT;   //  3,200,000  (out end)
constexpr long long G1 = G0 + 2LL * GE2;         // 10,000,000  (ei2 end; a2 follows)

constexpr unsigned CHUNK = 400000;    // pse slots per XCD-chunk

// ---- ws layout (floats), 56.8 MB ----
constexpr size_t W_ESC  = 0;          // GE2: alpha slots (self at GE+u, GE1+u)
constexpr size_t W_LG   = 3400000;    // GE2: logits (separate -> no aliasing in hot loops)
constexpr size_t W_XL1H = 6800000;    // N*HID bf16
constexpr size_t W_XR1  = 7600000;    // N*HID f32
constexpr size_t W_XL2H = 9200000;    // N*OUT bf16
constexpr size_t W_XR2  = 10800000;   // N*OUT f32
constexpr size_t W_RP   = 14000000;   // rowptr N+1 (int)
constexpr size_t W_CNT  = 14100004;   // cnt N (int)
constexpr size_t W_BS   = 14200004;   // scan block sums (256)
constexpr size_t W_SEA  = 14200260;
constexpr size_t W_WPI  = 14200261;
constexpr size_t W_END  = 14200264;

DEVFN int gidx(const int* __restrict__ ei, long long i, int wpi) {
    return ei[(size_t)i * (size_t)wpi];
}
DEVFN unsigned short f2b(float f) {               // f32 -> bf16 RNE
    unsigned u = __float_as_uint(f);
    unsigned r = ((u >> 16) & 1u) + 0x7fffu;
    return (unsigned short)((u + r) >> 16);
}
DEVFN float b2fl(unsigned u) { return __uint_as_float(u << 16); }
DEVFN float b2fh(unsigned u) { return __uint_as_float(u & 0xffff0000u); }

__global__ void gl_sentinel(float* outb) {        // ws too small -> Output 2 ~ 3840
    if (threadIdx.x == 0 && blockIdx.x == 0) outb[G1] = 3840.0f;
}

__global__ void gl_detect(const int* __restrict__ ei, int* flag) {
    int t = threadIdx.x;
    int v = ei[2 * t + 1];
    unsigned long long nz = __ballot(v != 0);
    if (t == 0) *flag = (nz == 0ull) ? 2 : 1;
}

__global__ void gl_sum(const float* __restrict__ p, int n, float* __restrict__ out) {
    float s = 0.f;
    for (int i = blockIdx.x * blockDim.x + threadIdx.x; i < n; i += gridDim.x * blockDim.x)
        s += p[i];
    #pragma unroll
    for (int o = 32; o > 0; o >>= 1) s += __shfl_down(s, o);
    __shared__ float ls[4];
    if ((threadIdx.x & 63) == 0) ls[threadIdx.x >> 6] = s;
    __syncthreads();
    if (threadIdx.x == 0) atomicAdd(out, ls[0] + ls[1] + ls[2] + ls[3]);
}

__global__ __launch_bounds__(256) void gl_projA(const float* __restrict__ x,
        const float* __restrict__ Wl, const float* __restrict__ Wr,
        unsigned short* __restrict__ xlh, float* __restrict__ xr) {
    __shared__ float sWl[GEMB * GHID], sWr[GEMB * GHID], sx[16 * GEMB];
    for (int i = threadIdx.x; i < GEMB * GHID; i += 256) { sWl[i] = Wl[i]; sWr[i] = Wr[i]; }
    int base = blockIdx.x * 16;
    for (int i = threadIdx.x; i < 16 * GEMB; i += 256) sx[i] = x[(size_t)base * GEMB + i];
    __syncthreads();
    int ln = threadIdx.x >> 4, ch = threadIdx.x & 15;
    float al = 0.f, ar = 0.f;
    #pragma unroll 8
    for (int k = 0; k < GEMB; ++k) {
        float xv = sx[ln * GEMB + k];
        al = fmaf(xv, sWl[k * GHID + ch], al);
        ar = fmaf(xv, sWr[k * GHID + ch], ar);
    }
    xlh[(size_t)(base + ln) * GHID + ch] = f2b(al);
    xr[(size_t)(base + ln) * GHID + ch] = ar;
}

__global__ __launch_bounds__(256) void gl_projB(const float* __restrict__ h,
        const float* __restrict__ Wl, const float* __restrict__ Wr,
        unsigned short* __restrict__ xlh, float* __restrict__ xr) {
    __shared__ float sWl[GHID * GOUT], sWr[GHID * GOUT], sx[8 * GHID];
    for (int i = threadIdx.x; i < GHID * GOUT; i += 256) { sWl[i] = Wl[i]; sWr[i] = Wr[i]; }
    int base = blockIdx.x * 8;
    for (int i = threadIdx.x; i < 8 * GHID; i += 256) sx[i] = h[(size_t)base * GHID + i];
    __syncthreads();
    int ln = threadIdx.x >> 5, ch = threadIdx.x & 31;
    float al = 0.f, ar = 0.f;
    #pragma unroll
    for (int k = 0; k < GHID; ++k) {
        float xv = sx[ln * GHID + k];
        al = fmaf(xv, sWl[k * GOUT + ch], al);
        ar = fmaf(xv, sWr[k * GOUT + ch], ar);
    }
    xlh[(size_t)(base + ln) * GOUT + ch] = f2b(al);
    xr[(size_t)(base + ln) * GOUT + ch] = ar;
}

// ---- hist: count per dst, store per-edge local rank only (12.8 MB) ----
__global__ void gl_hist(const int* __restrict__ ei, const int* __restrict__ wpip,
                        int* __restrict__ cnt, int* __restrict__ rank) {
    int e = blockIdx.x * blockDim.x + threadIdx.x;
    if (e >= GE) return;
    int wpi = *wpip;
    int dst = gidx(ei, (long long)GE + e, wpi);
    rank[e] = atomicAdd(&cnt[dst], 1);
}

__global__ __launch_bounds__(1024) void gl_scan1(const int* __restrict__ cnt,
                                                 int* __restrict__ rp, int* __restrict__ bs) {
    __shared__ int s[1024];
    int t = threadIdx.x, u = blockIdx.x * 1024 + t;
    s[t] = (u < GN) ? cnt[u] : 0;
    __syncthreads();
    for (int off = 1; off < 1024; off <<= 1) {
        int a = (t >= off) ? s[t - off] : 0;
        __syncthreads();
        s[t] += a;
        __syncthreads();
    }
    if (u < GN) rp[u + 1] = s[t];
    if (t == 1023) bs[blockIdx.x] = s[1023];
}
__global__ void gl_scan2(int* __restrict__ bs, int nb) {
    __shared__ int s[128];
    int t = threadIdx.x;
    s[t] = (t < nb) ? bs[t] : 0;
    __syncthreads();
    for (int off = 1; off < 128; off <<= 1) {
        int a = (t >= off) ? s[t - off] : 0;
        __syncthreads();
        s[t] += a;
        __syncthreads();
    }
    if (t < nb) bs[t] = (t == 0) ? 0 : s[t - 1];
}
__global__ void gl_scan3(int* __restrict__ rp, const int* __restrict__ bs) {
    int u = blockIdx.x * blockDim.x + threadIdx.x;
    if (u < GN) rp[u + 1] += bs[u >> 10];
    if (u == 0) rp[0] = 0;
}

// ---- slots: inv[e] = rp[dst] + rank[e]  (dst re-read from L3-resident ei) ----
__global__ void gl_slots(const int* __restrict__ ei, const int* __restrict__ wpip,
                         const int* __restrict__ rank, const int* __restrict__ rp,
                         int* __restrict__ inv) {
    int e = blockIdx.x * blockDim.x + threadIdx.x;
    if (e >= GE) return;
    int wpi = *wpip;
    int dst = gidx(ei, (long long)GE + e, wpi);
    inv[e] = rp[dst] + rank[e];
}

// ---- scatter: chunk-per-XCD (full-line writeback) ----
__global__ __launch_bounds__(256) void gl_scatter(const int* __restrict__ ei,
        const int* __restrict__ wpip, const float* __restrict__ eattr,
        const int* __restrict__ inv, int2* __restrict__ pse) {
    int wpi = *wpip;
    unsigned ck = blockIdx.x & 7;
    int stride = (gridDim.x >> 3) * 256;
    for (int e = (blockIdx.x >> 3) * 256 + threadIdx.x; e < GE; e += stride) {
        int slot = inv[e];
        if ((unsigned)slot / CHUNK == ck) {
            int src = gidx(ei, e, wpi);
            pse[slot] = make_int2(src, __float_as_int(eattr[e]));
        }
    }
}

// ------- fused layer 1: 4 lanes/edge, 16 edges in flight/wave (HID=16) -------
__global__ __launch_bounds__(256) void gl_L1(const int* __restrict__ rp,
        const int2* __restrict__ pse, const float* __restrict__ sea,
        const unsigned short* __restrict__ xlh, const float* __restrict__ xr,
        const float* __restrict__ We, const float* __restrict__ att,
        const float* __restrict__ b1, float* __restrict__ esc,
        float* __restrict__ lg, float* __restrict__ h1) {
    int u = blockIdx.x * 4 + (threadIdx.x >> 6);
    int lane = threadIdx.x & 63, sg = lane >> 2, ln4 = lane & 3;
    int beg = rp[u], end = rp[u + 1];
    float4 we = *(const float4*)(We + ln4 * 4);
    float4 at = *(const float4*)(att + ln4 * 4);
    float4 xru = *(const float4*)(xr + (size_t)u * GHID + ln4 * 4);
    float mx = -3.0e38f, pd = 0.f;
    float4 acc = make_float4(0.f, 0.f, 0.f, 0.f);
    int i = beg + sg;
    int2 p = (i < end) ? pse[i] : make_int2(0, 0);        // rotated prefetch
    for (; i < end; i += 16) {
        int inx = i + 16;
        int2 pn = (inx < end) ? pse[inx] : make_int2(0, 0);
        uint2 h = *(const uint2*)(xlh + (size_t)p.x * GHID + ln4 * 4);
        float ea = __int_as_float(p.y);
        float x0 = b2fl(h.x), x1 = b2fh(h.x), x2 = b2fl(h.y), x3 = b2fh(h.y);
        float v, s = 0.f;
        v = x0 + xru.x + ea * we.x; v = v > 0.f ? v : GNEG * v; s = fmaf(v, at.x, s);
        v = x1 + xru.y + ea * we.y; v = v > 0.f ? v : GNEG * v; s = fmaf(v, at.y, s);
        v = x2 + xru.z + ea * we.z; v = v > 0.f ? v : GNEG * v; s = fmaf(v, at.z, s);
        v = x3 + xru.w + ea * we.w; v = v > 0.f ? v : GNEG * v; s = fmaf(v, at.w, s);
        s += __shfl_xor(s, 1); s += __shfl_xor(s, 2);
        if (ln4 == 0) lg[i] = s;
        float nm = fmaxf(mx, s);
        float sc = __expf(mx - nm), pp = __expf(s - nm);
        pd = pd * sc + pp;
        acc.x = acc.x * sc + pp * x0; acc.y = acc.y * sc + pp * x1;
        acc.z = acc.z * sc + pp * x2; acc.w = acc.w * sc + pp * x3;
        mx = nm;
        p = pn;
    }
    float lgself = 0.f;
    if (sg == 0) {                                  // self-loop (ea = mean(edge_attr))
        uint2 h = *(const uint2*)(xlh + (size_t)u * GHID + ln4 * 4);
        float ea = sea[0] * (1.f / (float)GE);
        float x0 = b2fl(h.x), x1 = b2fh(h.x), x2 = b2fl(h.y), x3 = b2fh(h.y);
        float v, s = 0.f;
        v = x0 + xru.x + ea * we.x; v = v > 0.f ? v : GNEG * v; s = fmaf(v, at.x, s);
        v = x1 + xru.y + ea * we.y; v = v > 0.f ? v : GNEG * v; s = fmaf(v, at.y, s);
        v = x2 + xru.z + ea * we.z; v = v > 0.f ? v : GNEG * v; s = fmaf(v, at.z, s);
        v = x3 + xru.w + ea * we.w; v = v > 0.f ? v : GNEG * v; s = fmaf(v, at.w, s);
        s += __shfl_xor(s, 1); s += __shfl_xor(s, 2);
        lgself = s;
        float nm = fmaxf(mx, s);
        float sc = __expf(mx - nm), pp = __expf(s - nm);
        pd = pd * sc + pp;
        acc.x = acc.x * sc + pp * x0; acc.y = acc.y * sc + pp * x1;
        acc.z = acc.z * sc + pp * x2; acc.w = acc.w * sc + pp * x3;
        mx = nm;
    }
    #pragma unroll
    for (int o = 4; o <= 32; o <<= 1) {             // merge 16 subgroups
        float mo = __shfl_xor(mx, o), po = __shfl_xor(pd, o);
        float a0 = __shfl_xor(acc.x, o), a1 = __shfl_xor(acc.y, o);
        float a2 = __shfl_xor(acc.z, o), a3 = __shfl_xor(acc.w, o);
        float nm = fmaxf(mx, mo);
        float sa = __expf(mx - nm), sb = __expf(mo - nm);
        pd = pd * sa + po * sb;
        acc.x = acc.x * sa + a0 * sb; acc.y = acc.y * sa + a1 * sb;
        acc.z = acc.z * sa + a2 * sb; acc.w = acc.w * sa + a3 * sb;
        mx = nm;
    }
    float dinv = 1.f / pd;
    __threadfence_block();
    for (int j = beg + lane; j < end; j += 64)      // alpha pass (coalesced)
        esc[j] = __expf(lg[j] - mx) * dinv;
    if (lane == 0) esc[GE + u] = __expf(lgself - mx) * dinv;
    if (lane < 4) {
        float4 b = *(const float4*)(b1 + lane * 4);
        float4 o;
        o.x = acc.x * dinv + b.x; o.y = acc.y * dinv + b.y;
        o.z = acc.z * dinv + b.z; o.w = acc.w * dinv + b.w;
        o.x = o.x > 0.f ? o.x : 0.f; o.y = o.y > 0.f ? o.y : 0.f;
        o.z = o.z > 0.f ? o.z : 0.f; o.w = o.w > 0.f ? o.w : 0.f;
        *(float4*)(h1 + (size_t)u * GHID + lane * 4) = o;   // fused bias+relu
    }
}

// ------- fused layer 2: 8 lanes/edge, 8 edges in flight/wave (OUT=32) -------
__global__ __launch_bounds__(256) void gl_L2(const int* __restrict__ rp,
        const int2* __restrict__ pse,
        const unsigned short* __restrict__ xlh, const float* __restrict__ xr,
        const float* __restrict__ We, const float* __restrict__ att,
        const float* __restrict__ b2, float* __restrict__ esc,
        float* __restrict__ lg, float* __restrict__ out0) {
    int u = blockIdx.x * 4 + (threadIdx.x >> 6);
    int lane = threadIdx.x & 63, sg = lane >> 3, ln8 = lane & 7;
    int beg = rp[u], end = rp[u + 1];
    float4 we = *(const float4*)(We + ln8 * 4);
    float4 at = *(const float4*)(att + ln8 * 4);
    float4 xru = *(const float4*)(xr + (size_t)u * GOUT + ln8 * 4);
    float mx = -3.0e38f, pd = 0.f;
    float4 acc = make_float4(0.f, 0.f, 0.f, 0.f);
    int i = beg + sg;
    int2 p = (i < end) ? pse[i] : make_int2(0, 0);        // rotated prefetch
    float ea = (i < end) ? esc[i] : 0.f;
    for (; i < end; i += 8) {
        int inx = i + 8;
        int2 pn = (inx < end) ? pse[inx] : make_int2(0, 0);
        float ean = (inx < end) ? esc[inx] : 0.f;
        uint2 h = *(const uint2*)(xlh + (size_t)p.x * GOUT + ln8 * 4);
        float x0 = b2fl(h.x), x1 = b2fh(h.x), x2 = b2fl(h.y), x3 = b2fh(h.y);
        float v, s = 0.f;
        v = x0 + xru.x + ea * we.x; v = v > 0.f ? v : GNEG * v; s = fmaf(v, at.x, s);
        v = x1 + xru.y + ea * we.y; v = v > 0.f ? v : GNEG * v; s = fmaf(v, at.y, s);
        v = x2 + xru.z + ea * we.z; v = v > 0.f ? v : GNEG * v; s = fmaf(v, at.z, s);
        v = x3 + xru.w + ea * we.w; v = v > 0.f ? v : GNEG * v; s = fmaf(v, at.w, s);
        s += __shfl_xor(s, 1); s += __shfl_xor(s, 2); s += __shfl_xor(s, 4);
        if (ln8 == 0) lg[i] = s;
        float nm = fmaxf(mx, s);
        float sc = __expf(mx - nm), pp = __expf(s - nm);
        pd = pd * sc + pp;
        acc.x = acc.x * sc + pp * x0; acc.y = acc.y * sc + pp * x1;
        acc.z = acc.z * sc + pp * x2; acc.w = acc.w * sc + pp * x3;
        mx = nm;
        p = pn; ea = ean;
    }
    float lgs = 0.f;
    if (sg < 2) {   // two self-loops: sg0 -> ea=alpha1_self, sg1 -> ea=N/E1
        float eas = (sg == 0) ? esc[GE + u] : GEA2;
        uint2 h = *(const uint2*)(xlh + (size_t)u * GOUT + ln8 * 4);
        float x0 = b2fl(h.x), x1 = b2fh(h.x), x2 = b2fl(h.y), x3 = b2fh(h.y);
        float v, s = 0.f;
        v = x0 + xru.x + eas * we.x; v = v > 0.f ? v : GNEG * v; s = fmaf(v, at.x, s);
        v = x1 + xru.y + eas * we.y; v = v > 0.f ? v : GNEG * v; s = fmaf(v, at.y, s);
        v = x2 + xru.z + eas * we.z; v = v > 0.f ? v : GNEG * v; s = fmaf(v, at.z, s);
        v = x3 + xru.w + eas * we.w; v = v > 0.f ? v : GNEG * v; s = fmaf(v, at.w, s);
        s += __shfl_xor(s, 1); s += __shfl_xor(s, 2); s += __shfl_xor(s, 4);
        lgs = s;
        float nm = fmaxf(mx, s);
        float sc = __expf(mx - nm), pp = __expf(s - nm);
        pd = pd * sc + pp;
        acc.x = acc.x * sc + pp * x0; acc.y = acc.y * sc + pp * x1;
        acc.z = acc.z * sc + pp * x2; acc.w = acc.w * sc + pp * x3;
        mx = nm;
    }
    #pragma unroll
    for (int o = 8; o <= 32; o <<= 1) {             // merge 8 subgroups
        float mo = __shfl_xor(mx, o), po = __shfl_xor(pd, o);
        float a0 = __shfl_xor(acc.x, o), a1 = __shfl_xor(acc.y, o);
        float a2 = __shfl_xor(acc.z, o), a3 = __shfl_xor(acc.w, o);
        float nm = fmaxf(mx, mo);
        float sa = __expf(mx - nm), sb = __expf(mo - nm);
        pd = pd * sa + po * sb;
        acc.x = acc.x * sa + a0 * sb; acc.y = acc.y * sa + a1 * sb;
        acc.z = acc.z * sa + a2 * sb; acc.w = acc.w * sa + a3 * sb;
        mx = nm;
    }
    float dinv = 1.f / pd;
    __threadfence_block();
    for (int j = beg + lane; j < end; j += 64)      // alpha2 pass (coalesced)
        esc[j] = __expf(lg[j] - mx) * dinv;
    if (lane == 0) esc[GE + u]  = __expf(lgs - mx) * dinv;
    if (lane == 8) esc[GE1 + u] = __expf(lgs - mx) * dinv;
    if (lane < 8) {
        float4 b = *(const float4*)(b2 + lane * 4);
        float4 o;
        o.x = acc.x * dinv + b.x; o.y = acc.y * dinv + b.y;
        o.z = acc.z * dinv + b.z; o.w = acc.w * dinv + b.w;
        *(float4*)(out0 + (size_t)u * GOUT + lane * 4) = o;
    }
}

// fused epilogue: ei2 (2 floats) + a2 (1 float) per index, one pass.
__global__ void gl_ep(const int* __restrict__ ei, const int* __restrict__ wpip,
                      const int* __restrict__ inv, const float* __restrict__ esc,
                      float* __restrict__ outb) {
    int c = blockIdx.x * blockDim.x + threadIdx.x;
    if (c >= GE2) return;
    int wpi = *wpip;
    int s, dd;
    float av;
    if (c < GE) {
        s = gidx(ei, c, wpi);
        dd = gidx(ei, (long long)GE + c, wpi);
        av = esc[inv[c]];
    } else if (c < GE1) {
        s = dd = c - GE;
        av = esc[c];
    } else {
        s = dd = c - GE1;
        av = esc[c];
    }
    outb[G0 + c]       = (float)s;
    outb[G0 + GE2 + c] = (float)dd;
    outb[G1 + c]       = av;
}

extern "C" void kernel_launch(void* const* d_in, const int* in_sizes, int n_in,
                              void* d_out, int out_size, void* d_ws, size_t ws_size,
                              hipStream_t stream) {
    const float* x     = (const float*)d_in[0];
    const int*   ei    = (const int*)d_in[1];
    const float* eattr = (const float*)d_in[2];
    const float* W1l   = (const float*)d_in[3];
    const float* W1r   = (const float*)d_in[4];
    const float* W1e   = (const float*)d_in[5];
    const float* att1  = (const float*)d_in[6];
    const float* b1    = (const float*)d_in[7];
    const float* W2l   = (const float*)d_in[8];
    const float* W2r   = (const float*)d_in[9];
    const float* W2e   = (const float*)d_in[10];
    const float* att2  = (const float*)d_in[11];
    const float* b2    = (const float*)d_in[12];
    float* outf = (float*)d_out;

    float* ws = (float*)d_ws;
    if (W_END * sizeof(float) > ws_size) {          // 56.8 MB needed
        gl_sentinel<<<1, 64, 0, stream>>>(outf);
        return;
    }

    float*          esc  = ws + W_ESC;
    float*          lg   = ws + W_LG;
    unsigned short* xl1h = (unsigned short*)(ws + W_XL1H);
    float*          xr1  = ws + W_XR1;
    unsigned short* xl2h = (unsigned short*)(ws + W_XL2H);
    float*          xr2  = ws + W_XR2;
    int*            rp   = (int*)(ws + W_RP);
    int*            cnt  = (int*)(ws + W_CNT);
    int*            bs   = (int*)(ws + W_BS);
    float*          sea  = ws + W_SEA;
    int*            wpi  = (int*)(ws + W_WPI);

    // d_out scratch (each region reused strictly sequentially):
    //   rank: [G0, G0+GE) ints — consumed by gl_slots, THEN pse overwrites.
    //   pse : [G0, G0+2*GE) = ei2 region (6.8M floats >= 6.4M) — killed by gl_ep.
    //   inv : [G1, G1+GE)   = a2 region — read-then-overwritten by gl_ep.
    int*   rank = (int*)(outf + G0);
    int2*  pse  = (int2*)(outf + G0);
    int*   inv  = (int*)(outf + G1);
    float* h1   = outf;                             // chunk0, killed by L2's out0

    hipMemsetAsync(cnt, 0, GN * sizeof(int), stream);
    hipMemsetAsync(sea, 0, 2 * sizeof(float), stream);

    gl_detect<<<1, 64, 0, stream>>>(ei, wpi);
    gl_sum<<<1024, 256, 0, stream>>>(eattr, GE, sea);
    gl_projA<<<GN / 16, 256, 0, stream>>>(x, W1l, W1r, xl1h, xr1);

    int nbe = (GE + 255) / 256;
    gl_hist<<<nbe, 256, 0, stream>>>(ei, wpi, cnt, rank);
    gl_scan1<<<(GN + 1023) / 1024, 1024, 0, stream>>>(cnt, rp, bs);
    gl_scan2<<<1, 128, 0, stream>>>(bs, (GN + 1023) / 1024);
    gl_scan3<<<(GN + 255) / 256, 256, 0, stream>>>(rp, bs);
    gl_slots<<<nbe, 256, 0, stream>>>(ei, wpi, rank, rp, inv);
    gl_scatter<<<8192, 256, 0, stream>>>(ei, wpi, eattr, inv, pse);

    gl_L1<<<GN / 4, 256, 0, stream>>>(rp, pse, sea, xl1h, xr1, W1e, att1, b1, esc, lg, h1);
    gl_projB<<<GN / 8, 256, 0, stream>>>(h1, W2l, W2r, xl2h, xr2);
    gl_L2<<<GN / 4, 256, 0, stream>>>(rp, pse, xl2h, xr2, W2e, att2, b2, esc, lg, outf);
    gl_ep<<<(GE2 + 255) / 256, 256, 0, stream>>>(ei, wpi, inv, esc, outf);
}